// Round 13
// baseline (337.884 us; speedup 1.0000x reference)
//
#include <hip/hip_runtime.h>
#include <hip/hip_bf16.h>
#include <math.h>

// Stage 0: single merged cast kernel: x, w_qkv, w_out -> bf16
// Stage 1: merged projection GEMM (one launch, 768 blocks):
//          blocks 0..511:  QK  = x * Wqk^T -> q,k bf16 [B,H,S,128]
//          blocks 512..767: Vt = Wv * x^T  -> vt bf16 [B,H,128,S] (sigma)
// Stage 2: MFMA flash attention (window=512, QBLK=256, dbuf KV, kb-skip)
// Stage 3: 256^2 GEMM (out-proj) -> d_out fp32
//
// GEMM K-loop (R10-validated): full LDS double-buffer, ONE __syncthreads per
// tile; 24 ds_read_b128 + 64 MFMA barrier-free interval; all K-loop VMEM is
// asm gload_lds (single accounting).

#define SEQ   4096
#define BATCH 2
#define EMBED 2048
#define HEADS 16
#define HDIM  128
#define NELEM (BATCH * SEQ * EMBED)  // 16777216
#define SCL2E (0.088388347648318447f * 1.4426950408889634f)  // 1/sqrt(128)*log2(e)

typedef __attribute__((ext_vector_type(8))) short short8;
typedef __attribute__((ext_vector_type(4))) float f32x4;

__device__ __forceinline__ unsigned short f2bf(float f) {
    unsigned int u = __float_as_uint(f);
    u = (u + 0x7fff + ((u >> 16) & 1)) >> 16;  // round-to-nearest-even
    return (unsigned short)u;
}

__device__ __forceinline__ unsigned int cvt_pk_bf16(float a, float b) {
    unsigned int r;
    asm volatile("v_cvt_pk_bf16_f32 %0, %1, %2" : "=v"(r) : "v"(a), "v"(b));
    return r;
}

// ---------------------------------------------------------------------------
// merged fp32 -> bf16 cast for all three inputs, 8 elems/thread
// ---------------------------------------------------------------------------
__global__ void cast3_kernel(const float* __restrict__ x,
                             const float* __restrict__ wq,
                             const float* __restrict__ wo,
                             unsigned short* __restrict__ xb,
                             unsigned short* __restrict__ wqb,
                             unsigned short* __restrict__ wob)
{
    const int nx = NELEM / 8;
    const int nq = 3 * EMBED * EMBED / 8;
    const int no = EMBED * EMBED / 8;
    int i = blockIdx.x * blockDim.x + threadIdx.x;
    const float* s;
    unsigned short* d;
    int j;
    if (i < nx)                { s = x;  d = xb;  j = i; }
    else if (i < nx + nq)      { s = wq; d = wqb; j = i - nx; }
    else if (i < nx + nq + no) { s = wo; d = wob; j = i - nx - nq; }
    else return;
    const float4 v0 = ((const float4*)s)[2 * j];
    const float4 v1 = ((const float4*)s)[2 * j + 1];
    union { unsigned short us[8]; uint4 u4; } o;
    o.us[0] = f2bf(v0.x); o.us[1] = f2bf(v0.y); o.us[2] = f2bf(v0.z); o.us[3] = f2bf(v0.w);
    o.us[4] = f2bf(v1.x); o.us[5] = f2bf(v1.y); o.us[6] = f2bf(v1.z); o.us[7] = f2bf(v1.w);
    ((uint4*)d)[j] = o.u4;
}

// ---------------------------------------------------------------------------
// Merged projection GEMM. 768 blocks x 512 thr. K = 2048 for both.
//   blk < 512 : mode1, A = xb [8192,2048], B = Wqk [4096,2048], grid (16,32)
//   blk >= 512: mode2, A = Wv [2048,2048], B = xb [8192,2048],  grid (32,8)
// K-loop identical (R10-validated). Epilogues are the R10/R12 scatters.
// ---------------------------------------------------------------------------
__global__ __launch_bounds__(512)
void gemm_proj_kernel(const unsigned short* __restrict__ xb,
                      const unsigned short* __restrict__ wqkvb,
                      unsigned short* __restrict__ Qo,
                      unsigned short* __restrict__ Ko,
                      unsigned short* __restrict__ Vt)
{
    __shared__ __align__(16) char lds[131072];
    const int K = EMBED;

    const int tid  = threadIdx.x;
    const int lane = tid & 63;
    const int w    = tid >> 6;
    const int wm   = w >> 2;
    const int wn   = w & 3;
    const int l16  = lane & 15;
    const int kg   = lane >> 4;

    const int blk   = blockIdx.x;
    const int mode  = (blk < 512) ? 1 : 2;
    const int bidl  = (mode == 1) ? blk : blk - 512;
    const int gx    = (mode == 1) ? 16 : 32;          // n-tiles
    const int nwg   = (mode == 1) ? 512 : 256;
    const unsigned short* A = (mode == 1) ? xb : (wqkvb + (size_t)2 * EMBED * EMBED);
    const unsigned short* B = (mode == 1) ? wqkvb : xb;

    // m-major XCD chunking per sub-grid (R5-validated)
    const int cpx  = nwg >> 3;
    const int swzb = (bidl & 7) * cpx + (bidl >> 3);
    const int m0   = (swzb / gx) * 256;
    const int n0   = (swzb % gx) * 256;

    const int srow = w * 8 + (lane >> 3);
    const int sch8 = ((lane & 7) ^ (lane >> 3)) * 8;

    auto stage = [&](const unsigned short* X, int rowbase, int t2, int ldsbase) {
#pragma unroll
        for (int u = 0; u < 2; ++u) {
            const unsigned short* g = X + (size_t)(rowbase + u * 64 + srow) * K
                                      + t2 * 64 + sch8;
            unsigned int lb = __builtin_amdgcn_readfirstlane(
                (unsigned int)(uintptr_t)(lds + ldsbase + u * 8192 + w * 1024));
            asm volatile("s_mov_b32 m0, %0\n\t"
                         "global_load_lds_dwordx4 %1, off"
                         :: "s"(lb), "v"(g) : "memory");
        }
    };
    auto rdA = [&](int p, int mf, int ks) -> short8 {
        return *(const short8*)(lds + p * 32768 + (wm * 128 + mf * 16 + l16) * 128
                                + (((ks * 4 + kg) ^ (l16 & 7)) << 4));
    };
    auto rdB = [&](int p, int nf, int ks) -> short8 {
        return *(const short8*)(lds + 65536 + p * 32768
                                + (wn * 64 + nf * 16 + l16) * 128
                                + (((ks * 4 + kg) ^ (l16 & 7)) << 4));
    };

    f32x4 acc[8][4];
#pragma unroll
    for (int i = 0; i < 8; ++i)
#pragma unroll
        for (int j = 0; j < 4; ++j) acc[i][j] = (f32x4)0.f;

    const int NT = K >> 6;  // 32

    stage(A, m0 + 0,   0, 0);
    stage(A, m0 + 128, 0, 16384);
    stage(B, n0 + 0,   0, 65536);
    stage(B, n0 + 128, 0, 65536 + 16384);
    __syncthreads();

    for (int t = 0; t < NT; ++t) {
        const int p = t & 1;
        if (t + 1 < NT) {
            stage(A, m0 + 0,   t + 1, (p ^ 1) * 32768);
            stage(A, m0 + 128, t + 1, (p ^ 1) * 32768 + 16384);
            stage(B, n0 + 0,   t + 1, 65536 + (p ^ 1) * 32768);
            stage(B, n0 + 128, t + 1, 65536 + (p ^ 1) * 32768 + 16384);
        }
        short8 bfr[4][2];
#pragma unroll
        for (int nf = 0; nf < 4; ++nf)
#pragma unroll
            for (int ks = 0; ks < 2; ++ks) bfr[nf][ks] = rdB(p, nf, ks);
#pragma unroll
        for (int mf = 0; mf < 8; ++mf) {
            const short8 a0 = rdA(p, mf, 0);
            const short8 a1 = rdA(p, mf, 1);
#pragma unroll
            for (int nf = 0; nf < 4; ++nf) {
                acc[mf][nf] = __builtin_amdgcn_mfma_f32_16x16x32_bf16(
                    a0, bfr[nf][0], acc[mf][nf], 0, 0, 0);
                acc[mf][nf] = __builtin_amdgcn_mfma_f32_16x16x32_bf16(
                    a1, bfr[nf][1], acc[mf][nf], 0, 0, 0);
            }
        }
        __syncthreads();
    }

    if (mode == 1) {
        const int cb = n0 + wn * 64;          // one head slice (q or k)
        unsigned short* dst = (cb >> 11) ? Ko : Qo;
        const int h  = (cb >> 7) & 15;
        const int db = cb & 127;
#pragma unroll
        for (int fi = 0; fi < 8; ++fi)
#pragma unroll
            for (int r = 0; r < 4; ++r) {
                const int mrow = m0 + wm * 128 + fi * 16 + kg * 4 + r;
                const int b = mrow >> 12, s = mrow & 4095;
                unsigned short* drow = dst + ((size_t)((b << 4) + h) * SEQ + s) * HDIM
                                       + db + l16;
#pragma unroll
                for (int nf = 0; nf < 4; ++nf) drow[nf * 16] = f2bf(acc[fi][nf][r]);
            }
    } else {
#pragma unroll
        for (int fi = 0; fi < 8; ++fi)
#pragma unroll
            for (int r = 0; r < 4; ++r) {
                const int mrow = m0 + wm * 128 + fi * 16 + kg * 4 + r;
                const int h = mrow >> 7, d = mrow & 127;
#pragma unroll
                for (int nf = 0; nf < 4; ++nf) {
                    const int col = n0 + wn * 64 + nf * 16 + l16;
                    const int b = col >> 12, s = col & 4095;
                    const int sl = s & 63;
                    const int c = (sl & 0x23) | ((sl & 0x0C) << 1) | ((sl & 0x10) >> 2);
                    Vt[((size_t)((b << 4) + h) * HDIM + d) * SEQ + (s & ~63) + c] =
                        f2bf(acc[fi][nf][r]);
                }
            }
    }
}

// ---------------------------------------------------------------------------
// out-projection GEMM (R10-validated, MODE 0 path): C fp32 [M,N]
// ---------------------------------------------------------------------------
__global__ __launch_bounds__(512)
void gemm_out_kernel(const unsigned short* __restrict__ A,
                     const unsigned short* __restrict__ B,
                     float* __restrict__ C,
                     int M, int N, int K)
{
    __shared__ __align__(16) char lds[131072];

    const int tid  = threadIdx.x;
    const int lane = tid & 63;
    const int w    = tid >> 6;
    const int wm   = w >> 2;
    const int wn   = w & 3;
    const int l16  = lane & 15;
    const int kg   = lane >> 4;

    const int nwg  = gridDim.x * gridDim.y;
    const int bidl = blockIdx.y * gridDim.x + blockIdx.x;
    const int cpx  = nwg >> 3;
    const int swzb = (bidl & 7) * cpx + (bidl >> 3);
    const int m0   = (swzb / gridDim.x) * 256;
    const int n0   = (swzb % gridDim.x) * 256;

    const int srow = w * 8 + (lane >> 3);
    const int sch8 = ((lane & 7) ^ (lane >> 3)) * 8;

    auto stage = [&](const unsigned short* X, int rowbase, int t2, int ldsbase) {
#pragma unroll
        for (int u = 0; u < 2; ++u) {
            const unsigned short* g = X + (size_t)(rowbase + u * 64 + srow) * K
                                      + t2 * 64 + sch8;
            unsigned int lb = __builtin_amdgcn_readfirstlane(
                (unsigned int)(uintptr_t)(lds + ldsbase + u * 8192 + w * 1024));
            asm volatile("s_mov_b32 m0, %0\n\t"
                         "global_load_lds_dwordx4 %1, off"
                         :: "s"(lb), "v"(g) : "memory");
        }
    };
    auto rdA = [&](int p, int mf, int ks) -> short8 {
        return *(const short8*)(lds + p * 32768 + (wm * 128 + mf * 16 + l16) * 128
                                + (((ks * 4 + kg) ^ (l16 & 7)) << 4));
    };
    auto rdB = [&](int p, int nf, int ks) -> short8 {
        return *(const short8*)(lds + 65536 + p * 32768
                                + (wn * 64 + nf * 16 + l16) * 128
                                + (((ks * 4 + kg) ^ (l16 & 7)) << 4));
    };

    f32x4 acc[8][4];
#pragma unroll
    for (int i = 0; i < 8; ++i)
#pragma unroll
        for (int j = 0; j < 4; ++j) acc[i][j] = (f32x4)0.f;

    const int NT = K >> 6;

    stage(A, m0 + 0,   0, 0);
    stage(A, m0 + 128, 0, 16384);
    stage(B, n0 + 0,   0, 65536);
    stage(B, n0 + 128, 0, 65536 + 16384);
    __syncthreads();

    for (int t = 0; t < NT; ++t) {
        const int p = t & 1;
        if (t + 1 < NT) {
            stage(A, m0 + 0,   t + 1, (p ^ 1) * 32768);
            stage(A, m0 + 128, t + 1, (p ^ 1) * 32768 + 16384);
            stage(B, n0 + 0,   t + 1, 65536 + (p ^ 1) * 32768);
            stage(B, n0 + 128, t + 1, 65536 + (p ^ 1) * 32768 + 16384);
        }
        short8 bfr[4][2];
#pragma unroll
        for (int nf = 0; nf < 4; ++nf)
#pragma unroll
            for (int ks = 0; ks < 2; ++ks) bfr[nf][ks] = rdB(p, nf, ks);
#pragma unroll
        for (int mf = 0; mf < 8; ++mf) {
            const short8 a0 = rdA(p, mf, 0);
            const short8 a1 = rdA(p, mf, 1);
#pragma unroll
            for (int nf = 0; nf < 4; ++nf) {
                acc[mf][nf] = __builtin_amdgcn_mfma_f32_16x16x32_bf16(
                    a0, bfr[nf][0], acc[mf][nf], 0, 0, 0);
                acc[mf][nf] = __builtin_amdgcn_mfma_f32_16x16x32_bf16(
                    a1, bfr[nf][1], acc[mf][nf], 0, 0, 0);
            }
        }
        __syncthreads();
    }

#pragma unroll
    for (int fi = 0; fi < 8; ++fi)
#pragma unroll
        for (int r = 0; r < 4; ++r) {
            float* crow = C + (size_t)(m0 + wm * 128 + fi * 16 + kg * 4 + r) * N
                          + n0 + wn * 64 + l16;
#pragma unroll
            for (int nf = 0; nf < 4; ++nf) crow[nf * 16] = acc[fi][nf][r];
        }
}

// ---------------------------------------------------------------------------
// MFMA flash attention, QBLK=256 (R13): 1024 thr = 16 waves, each owning 16
// queries; 12 KV tiles of 64 per block (vs 10 per 128 queries before: -40%
// staging traffic and barrier iterations). Per-query tile set/order is
// identical to R12 (64-aligned gk0) -> bitwise-identical output. Per buf:
// K [64 keys][128 d] @ +0, Vt [128 d][64 sigma-keys] @ +16384; bufs @ 0/32768.
// Swapped QK^T; P lane-local via sigma; dbuf KV; wave-uniform kb-skip.
// ---------------------------------------------------------------------------
__global__ __launch_bounds__(1024)
void swa_mfma_kernel(const unsigned short* __restrict__ Qg,
                     const unsigned short* __restrict__ Kg,
                     const unsigned short* __restrict__ Vtg,
                     unsigned short* __restrict__ O /* bf16 [B,S,E] */)
{
    __shared__ __align__(16) char lds[65536];

    const int bid = blockIdx.x;
    const int qt  = bid & 15;            // SEQ/256 = 16 query tiles
    const int h   = (bid >> 4) & 15;
    const int b   = bid >> 8;
    const int q0  = qt * 256;
    const int tid  = threadIdx.x;
    const int w    = tid >> 6;           // 0..15
    const int lane = tid & 63;
    const int l16  = lane & 15;
    const int kg   = lane >> 4;
    const size_t base = (size_t)((b << 4) + h) * SEQ * HDIM;
    const int gq = q0 + w * 16 + l16;

    short8 qf[4];
#pragma unroll
    for (int kw = 0; kw < 4; ++kw)
        qf[kw] = *(const short8*)(Qg + base + (size_t)gq * HDIM + kw * 32 + kg * 8);

    f32x4 acc_o[8];
#pragma unroll
    for (int db = 0; db < 8; ++db) acc_o[db] = (f32x4)0.f;
    float m = -1e30f, l = 0.f;

    auto stageKV = [&](int kt, int buf) {
        const int gk0 = q0 - 512 + kt * 64;
        {   // K: 1024 chunks, row=key (tid>>4), 16 chunks/row, swz ch^(row&7)
            const int row = tid >> 4, ch = tid & 15;
            const char* g = (const char*)(Kg + base + (size_t)(gk0 + row) * HDIM
                                          + ((ch ^ (row & 7)) << 3));
            unsigned int lb = __builtin_amdgcn_readfirstlane(
                (unsigned int)(uintptr_t)(lds + buf * 32768 + w * 1024));
            asm volatile("s_mov_b32 m0, %0\n\t"
                         "global_load_lds_dwordx4 %1, off"
                         :: "s"(lb), "v"(g) : "memory");
        }
        {   // Vt: row=d (tid>>3), 8 chunks/row, swz ch^(d&7)
            const int d = tid >> 3, ch = tid & 7;
            const char* g = (const char*)(Vtg + base + (size_t)d * SEQ + gk0
                                          + ((ch ^ (d & 7)) << 3));
            unsigned int lb = __builtin_amdgcn_readfirstlane(
                (unsigned int)(uintptr_t)(lds + buf * 32768 + 16384 + w * 1024));
            asm volatile("s_mov_b32 m0, %0\n\t"
                         "global_load_lds_dwordx4 %1, off"
                         :: "s"(lb), "v"(g) : "memory");
        }
    };

    const int kt_start = (qt < 2) ? (8 - 4 * qt) : 0;
    stageKV(kt_start, 0);
    int cur = 0;

    for (int kt = kt_start; kt < 12; ++kt) {
        asm volatile("s_waitcnt vmcnt(0)" ::: "memory");
        __syncthreads();
        if (kt + 1 < 12) stageKV(kt + 1, cur ^ 1);

        const int gk0 = q0 - 512 + kt * 64;
        const char* ldsb = lds + cur * 32768;
        const int qlo = q0 + w * 16;
        const bool active = (gk0 <= qlo + 15) && (gk0 + 63 >= qlo - 512);
        if (active) {
            const int dqw = qlo - gk0;
            bool kbok[4];
#pragma unroll
            for (int kb = 0; kb < 4; ++kb)
                kbok[kb] = (kb * 16 <= dqw + 15) && (kb * 16 + 15 >= dqw - 512);

            f32x4 s4[4];
#pragma unroll
            for (int kb = 0; kb < 4; ++kb) s4[kb] = (f32x4)0.f;
#pragma unroll
            for (int kb = 0; kb < 4; ++kb) {
                if (kbok[kb]) {
#pragma unroll
                    for (int kw = 0; kw < 4; ++kw) {
                        short8 kf = *(const short8*)(ldsb + (kb * 16 + l16) * 256
                                                     + (((kw * 4 + kg) ^ (l16 & 7)) << 4));
                        s4[kb] = __builtin_amdgcn_mfma_f32_16x16x32_bf16(
                            kf, qf[kw], s4[kb], 0, 0, 0);
                    }
                }
            }

            const int dq = gq - gk0;
            float p[4][4];
            float tm = -1e30f;
#pragma unroll
            for (int kb = 0; kb < 4; ++kb)
#pragma unroll
                for (int r = 0; r < 4; ++r) {
                    const int koff = kb * 16 + kg * 4 + r;
                    const bool valid = (koff <= dq) && (koff >= dq - 512);
                    const float sv = valid ? s4[kb][r] * SCL2E : -1e30f;
                    p[kb][r] = sv;
                    tm = fmaxf(tm, sv);
                }
            tm = fmaxf(tm, __shfl_xor(tm, 16));
            tm = fmaxf(tm, __shfl_xor(tm, 32));
            const float mn   = fmaxf(m, tm);
            const float corr = __builtin_amdgcn_exp2f(m - mn);
            m = mn;
            l *= corr;
            float cr[4];
#pragma unroll
            for (int r = 0; r < 4; ++r) cr[r] = __shfl(corr, kg * 4 + r);
#pragma unroll
            for (int db = 0; db < 8; ++db)
#pragma unroll
                for (int r = 0; r < 4; ++r) acc_o[db][r] *= cr[r];

            float ts = 0.f;
#pragma unroll
            for (int kb = 0; kb < 4; ++kb)
#pragma unroll
                for (int r = 0; r < 4; ++r) {
                    const float pv = (p[kb][r] > -1e29f)
                                         ? __builtin_amdgcn_exp2f(p[kb][r] - m) : 0.f;
                    p[kb][r] = pv;
                    ts += pv;
                }
            ts += __shfl_xor(ts, 16);
            ts += __shfl_xor(ts, 32);
            l += ts;

            unsigned int dw[4][2];
#pragma unroll
            for (int kb = 0; kb < 4; ++kb) {
                dw[kb][0] = cvt_pk_bf16(p[kb][0], p[kb][1]);
                dw[kb][1] = cvt_pk_bf16(p[kb][2], p[kb][3]);
            }
#pragma unroll
            for (int w2 = 0; w2 < 2; ++w2) {
                if (!(kbok[2 * w2] || kbok[2 * w2 + 1])) continue;
                union { unsigned int u[4]; short8 v; } pu;
                pu.u[0] = dw[2 * w2][0];     pu.u[1] = dw[2 * w2][1];
                pu.u[2] = dw[2 * w2 + 1][0]; pu.u[3] = dw[2 * w2 + 1][1];
#pragma unroll
                for (int db = 0; db < 8; ++db) {
                    short8 vf = *(const short8*)(ldsb + 16384 + (db * 16 + l16) * 128
                                                 + (((w2 * 4 + kg) ^ (l16 & 7)) << 4));
                    acc_o[db] = __builtin_amdgcn_mfma_f32_16x16x32_bf16(
                        pu.v, vf, acc_o[db], 0, 0, 0);
                }
            }
        }
        cur ^= 1;
    }

    const float inv = 1.0f / l;
    float li[4];
#pragma unroll
    for (int r = 0; r < 4; ++r) li[r] = __shfl(inv, kg * 4 + r);
#pragma unroll
    for (int db = 0; db < 8; ++db)
#pragma unroll
        for (int r = 0; r < 4; ++r) {
            const int gqr = q0 + w * 16 + kg * 4 + r;
            O[((size_t)b * SEQ + gqr) * EMBED + h * HDIM + db * 16 + l16] =
                f2bf(acc_o[db][r] * li[r]);
        }
}

// ---------------------------------------------------------------------------
extern "C" void kernel_launch(void* const* d_in, const int* in_sizes, int n_in,
                              void* d_out, int out_size, void* d_ws, size_t ws_size,
                              hipStream_t stream)
{
    const float* x     = (const float*)d_in[0];
    const float* w_qkv = (const float*)d_in[1];
    const float* w_out = (const float*)d_in[2];
    float* out = (float*)d_out;

    char* ws = (char*)d_ws;
    unsigned short* xb    = (unsigned short*)(ws);
    unsigned short* wqkvb = (unsigned short*)(ws + 33554432);
    unsigned short* woutb = (unsigned short*)(ws + 58720256);
    unsigned short* qb    = (unsigned short*)(ws + 67108864);
    unsigned short* kb    = (unsigned short*)(ws + 100663296);
    unsigned short* vtb   = (unsigned short*)(ws + 134217728);
    unsigned short* attnb = (unsigned short*)(ws + 167772160);

    const int M = BATCH * SEQ;  // 8192
    dim3 blk(256);

    // merged casts
    hipLaunchKernelGGL(cast3_kernel, dim3(16384), blk, 0, stream,
                       x, w_qkv, w_out, xb, wqkvb, woutb);

    // merged QK + Vt projections: 768 blocks
    hipLaunchKernelGGL(gemm_proj_kernel, dim3(768), dim3(512), 0, stream,
                       xb, wqkvb, qb, kb, vtb);

    // attention: QBLK=256 -> 512 blocks x 1024 threads
    hipLaunchKernelGGL(swa_mfma_kernel, dim3(BATCH * HEADS * (SEQ / 256)), dim3(1024),
                       0, stream, qb, kb, vtb, attnb);

    // out projection: grid (8,32)
    hipLaunchKernelGGL(gemm_out_kernel, dim3(8, 32), dim3(512), 0, stream,
                       attnb, woutb, out, M, EMBED, EMBED);
}

// Round 14
// 330.907 us; speedup vs baseline: 1.0211x; 1.0211x over previous
//
#include <hip/hip_runtime.h>
#include <hip/hip_bf16.h>
#include <math.h>

// Stage 0: single merged cast kernel: x, w_qkv, w_out -> bf16
// Stage 1a: 256^2 bf16 MFMA GEMM (x * Wqk^T) -> q,k bf16 [B,H,S,128]
// Stage 1b: same (Wv * x^T) -> vt bf16 [B,H,128,S], sigma baked in
//           (separate launches -- R13 merge regressed: mixed-mode blocks
//            thrash per-XCD L2; 196 vs 181 us)
// Stage 2: MFMA flash attention (window=512, QBLK=256, dbuf KV, kb-skip)
// Stage 3: same GEMM -> d_out fp32
//
// GEMM K-loop (R10-validated): full LDS double-buffer, ONE __syncthreads per
// tile; 24 ds_read_b128 + 64 MFMA barrier-free interval; all K-loop VMEM is
// asm gload_lds (single accounting).

#define SEQ   4096
#define BATCH 2
#define EMBED 2048
#define HEADS 16
#define HDIM  128
#define NELEM (BATCH * SEQ * EMBED)  // 16777216
#define SCL2E (0.088388347648318447f * 1.4426950408889634f)  // 1/sqrt(128)*log2(e)

typedef __attribute__((ext_vector_type(8))) short short8;
typedef __attribute__((ext_vector_type(4))) float f32x4;

__device__ __forceinline__ unsigned short f2bf(float f) {
    unsigned int u = __float_as_uint(f);
    u = (u + 0x7fff + ((u >> 16) & 1)) >> 16;  // round-to-nearest-even
    return (unsigned short)u;
}

__device__ __forceinline__ unsigned int cvt_pk_bf16(float a, float b) {
    unsigned int r;
    asm volatile("v_cvt_pk_bf16_f32 %0, %1, %2" : "=v"(r) : "v"(a), "v"(b));
    return r;
}

// ---------------------------------------------------------------------------
// merged fp32 -> bf16 cast for all three inputs, 8 elems/thread
// ---------------------------------------------------------------------------
__global__ void cast3_kernel(const float* __restrict__ x,
                             const float* __restrict__ wq,
                             const float* __restrict__ wo,
                             unsigned short* __restrict__ xb,
                             unsigned short* __restrict__ wqb,
                             unsigned short* __restrict__ wob)
{
    const int nx = NELEM / 8;
    const int nq = 3 * EMBED * EMBED / 8;
    const int no = EMBED * EMBED / 8;
    int i = blockIdx.x * blockDim.x + threadIdx.x;
    const float* s;
    unsigned short* d;
    int j;
    if (i < nx)                { s = x;  d = xb;  j = i; }
    else if (i < nx + nq)      { s = wq; d = wqb; j = i - nx; }
    else if (i < nx + nq + no) { s = wo; d = wob; j = i - nx - nq; }
    else return;
    const float4 v0 = ((const float4*)s)[2 * j];
    const float4 v1 = ((const float4*)s)[2 * j + 1];
    union { unsigned short us[8]; uint4 u4; } o;
    o.us[0] = f2bf(v0.x); o.us[1] = f2bf(v0.y); o.us[2] = f2bf(v0.z); o.us[3] = f2bf(v0.w);
    o.us[4] = f2bf(v1.x); o.us[5] = f2bf(v1.y); o.us[6] = f2bf(v1.z); o.us[7] = f2bf(v1.w);
    ((uint4*)d)[j] = o.u4;
}

// ---------------------------------------------------------------------------
// 256x256 bf16 NT-GEMM: C[M,N] = A[M,K]*B[N,K]^T, fp32 accum. 512 thr, 8 waves
// (2M x 4N), per-wave 128x64 (acc[8][4]). BK=64, double-buffered 128 KiB LDS.
// MODE 0: C fp32 [M,N];  MODE 1: scatter bf16 q/k [B,H,S,128];
// MODE 2: scatter bf16 vt [B,H,128,S] with sigma permutation.
// ---------------------------------------------------------------------------
template <int MODE>
__global__ __launch_bounds__(512)
void gemm256_kernel(const unsigned short* __restrict__ A,
                    const unsigned short* __restrict__ B,
                    float* __restrict__ C,
                    unsigned short* __restrict__ P0,
                    unsigned short* __restrict__ P1,
                    int M, int N, int K)
{
    // Abuf[p] @ p*32768; Bbuf[p] @ 65536 + p*32768
    __shared__ __align__(16) char lds[131072];

    const int tid  = threadIdx.x;
    const int lane = tid & 63;
    const int w    = tid >> 6;       // 0..7
    const int wm   = w >> 2;         // 0..1
    const int wn   = w & 3;          // 0..3
    const int l16  = lane & 15;
    const int kg   = lane >> 4;

    // m-major XCD chunking (R5-validated)
    const int nwg  = gridDim.x * gridDim.y;
    const int bidl = blockIdx.y * gridDim.x + blockIdx.x;
    const int cpx  = nwg >> 3;
    const int swzb = (bidl & 7) * cpx + (bidl >> 3);
    const int m0   = (swzb / gridDim.x) * 256;
    const int n0   = (swzb % gridDim.x) * 256;

    // staging: per instr u, rows u*64 + w*8 + (lane>>3); source chunk
    // pre-swizzled so LDS[row][ch] = global[row][ch ^ (row&7)].
    const int srow = w * 8 + (lane >> 3);
    const int sch8 = ((lane & 7) ^ (lane >> 3)) * 8;

    auto stage = [&](const unsigned short* X, int rowbase, int t2, int ldsbase) {
#pragma unroll
        for (int u = 0; u < 2; ++u) {
            const unsigned short* g = X + (size_t)(rowbase + u * 64 + srow) * K
                                      + t2 * 64 + sch8;
            unsigned int lb = __builtin_amdgcn_readfirstlane(
                (unsigned int)(uintptr_t)(lds + ldsbase + u * 8192 + w * 1024));
            asm volatile("s_mov_b32 m0, %0\n\t"
                         "global_load_lds_dwordx4 %1, off"
                         :: "s"(lb), "v"(g) : "memory");
        }
    };
    auto rdA = [&](int p, int mf, int ks) -> short8 {
        return *(const short8*)(lds + p * 32768 + (wm * 128 + mf * 16 + l16) * 128
                                + (((ks * 4 + kg) ^ (l16 & 7)) << 4));
    };
    auto rdB = [&](int p, int nf, int ks) -> short8 {
        return *(const short8*)(lds + 65536 + p * 32768
                                + (wn * 64 + nf * 16 + l16) * 128
                                + (((ks * 4 + kg) ^ (l16 & 7)) << 4));
    };

    f32x4 acc[8][4];
#pragma unroll
    for (int i = 0; i < 8; ++i)
#pragma unroll
        for (int j = 0; j < 4; ++j) acc[i][j] = (f32x4)0.f;

    const int NT = K >> 6;  // K-tiles of 64 (K=2048 -> 32)

    // prologue: stage tile 0 into bufs 0; drain + barrier.
    stage(A, m0 + 0,   0, 0);
    stage(A, m0 + 128, 0, 16384);
    stage(B, n0 + 0,   0, 65536);
    stage(B, n0 + 128, 0, 65536 + 16384);
    __syncthreads();

    for (int t = 0; t < NT; ++t) {
        const int p = t & 1;
        // prefetch tile t+1 into bufs p^1 (issue first: max HBM-latency cover)
        if (t + 1 < NT) {
            stage(A, m0 + 0,   t + 1, (p ^ 1) * 32768);
            stage(A, m0 + 128, t + 1, (p ^ 1) * 32768 + 16384);
            stage(B, n0 + 0,   t + 1, 65536 + (p ^ 1) * 32768);
            stage(B, n0 + 128, t + 1, 65536 + (p ^ 1) * 32768 + 16384);
        }
        // barrier-free interval: 24 ds_reads + 64 MFMAs, compiler-interleaved
        short8 bfr[4][2];
#pragma unroll
        for (int nf = 0; nf < 4; ++nf)
#pragma unroll
            for (int ks = 0; ks < 2; ++ks) bfr[nf][ks] = rdB(p, nf, ks);
#pragma unroll
        for (int mf = 0; mf < 8; ++mf) {
            const short8 a0 = rdA(p, mf, 0);
            const short8 a1 = rdA(p, mf, 1);
#pragma unroll
            for (int nf = 0; nf < 4; ++nf) {
                acc[mf][nf] = __builtin_amdgcn_mfma_f32_16x16x32_bf16(
                    a0, bfr[nf][0], acc[mf][nf], 0, 0, 0);
                acc[mf][nf] = __builtin_amdgcn_mfma_f32_16x16x32_bf16(
                    a1, bfr[nf][1], acc[mf][nf], 0, 0, 0);
            }
        }
        // single boundary: vmcnt(0)+lgkmcnt(0)+s_barrier (compiler-emitted);
        // staged loads are ~1 tile old -> drain is cheap.
        __syncthreads();
    }

    // epilogue (R10-validated scatter)
    if (MODE == 1) {
        const int cb = n0 + wn * 64;          // 64-col wave tile: one head slice
        unsigned short* dst = (cb >> 11) ? P1 : P0;
        const int h  = (cb >> 7) & 15;
        const int db = cb & 127;
#pragma unroll
        for (int fi = 0; fi < 8; ++fi)
#pragma unroll
            for (int r = 0; r < 4; ++r) {
                const int mrow = m0 + wm * 128 + fi * 16 + kg * 4 + r;
                const int b = mrow >> 12, s = mrow & 4095;
                unsigned short* drow = dst + ((size_t)((b << 4) + h) * SEQ + s) * HDIM
                                       + db + l16;
#pragma unroll
                for (int nf = 0; nf < 4; ++nf) drow[nf * 16] = f2bf(acc[fi][nf][r]);
            }
    } else if (MODE == 2) {
#pragma unroll
        for (int fi = 0; fi < 8; ++fi)
#pragma unroll
            for (int r = 0; r < 4; ++r) {
                const int mrow = m0 + wm * 128 + fi * 16 + kg * 4 + r;
                const int h = mrow >> 7, d = mrow & 127;
#pragma unroll
                for (int nf = 0; nf < 4; ++nf) {
                    const int col = n0 + wn * 64 + nf * 16 + l16;
                    const int b = col >> 12, s = col & 4095;
                    const int sl = s & 63;
                    const int c = (sl & 0x23) | ((sl & 0x0C) << 1) | ((sl & 0x10) >> 2);
                    P0[((size_t)((b << 4) + h) * HDIM + d) * SEQ + (s & ~63) + c] =
                        f2bf(acc[fi][nf][r]);
                }
            }
    } else {
#pragma unroll
        for (int fi = 0; fi < 8; ++fi)
#pragma unroll
            for (int r = 0; r < 4; ++r) {
                float* crow = C + (size_t)(m0 + wm * 128 + fi * 16 + kg * 4 + r) * N
                              + n0 + wn * 64 + l16;
#pragma unroll
                for (int nf = 0; nf < 4; ++nf) crow[nf * 16] = acc[fi][nf][r];
            }
    }
}

// ---------------------------------------------------------------------------
// MFMA flash attention, QBLK=256 (R13-validated): 1024 thr = 16 waves, each
// owning 16 queries; 12 KV tiles of 64 per block. Per buf: K [64 keys][128 d]
// @ +0, Vt [128 d][64 sigma-keys] @ +16384; bufs @ 0/32768. Swapped QK^T;
// P lane-local via sigma; dbuf KV; wave-uniform kb-skip.
// ---------------------------------------------------------------------------
__global__ __launch_bounds__(1024)
void swa_mfma_kernel(const unsigned short* __restrict__ Qg,
                     const unsigned short* __restrict__ Kg,
                     const unsigned short* __restrict__ Vtg,
                     unsigned short* __restrict__ O /* bf16 [B,S,E] */)
{
    __shared__ __align__(16) char lds[65536];

    const int bid = blockIdx.x;
    const int qt  = bid & 15;            // SEQ/256 = 16 query tiles
    const int h   = (bid >> 4) & 15;
    const int b   = bid >> 8;
    const int q0  = qt * 256;
    const int tid  = threadIdx.x;
    const int w    = tid >> 6;           // 0..15
    const int lane = tid & 63;
    const int l16  = lane & 15;
    const int kg   = lane >> 4;
    const size_t base = (size_t)((b << 4) + h) * SEQ * HDIM;
    const int gq = q0 + w * 16 + l16;

    short8 qf[4];
#pragma unroll
    for (int kw = 0; kw < 4; ++kw)
        qf[kw] = *(const short8*)(Qg + base + (size_t)gq * HDIM + kw * 32 + kg * 8);

    f32x4 acc_o[8];
#pragma unroll
    for (int db = 0; db < 8; ++db) acc_o[db] = (f32x4)0.f;
    float m = -1e30f, l = 0.f;

    auto stageKV = [&](int kt, int buf) {
        const int gk0 = q0 - 512 + kt * 64;
        {   // K: 1024 chunks, row=key (tid>>4), 16 chunks/row, swz ch^(row&7)
            const int row = tid >> 4, ch = tid & 15;
            const char* g = (const char*)(Kg + base + (size_t)(gk0 + row) * HDIM
                                          + ((ch ^ (row & 7)) << 3));
            unsigned int lb = __builtin_amdgcn_readfirstlane(
                (unsigned int)(uintptr_t)(lds + buf * 32768 + w * 1024));
            asm volatile("s_mov_b32 m0, %0\n\t"
                         "global_load_lds_dwordx4 %1, off"
                         :: "s"(lb), "v"(g) : "memory");
        }
        {   // Vt: row=d (tid>>3), 8 chunks/row, swz ch^(d&7)
            const int d = tid >> 3, ch = tid & 7;
            const char* g = (const char*)(Vtg + base + (size_t)d * SEQ + gk0
                                          + ((ch ^ (d & 7)) << 3));
            unsigned int lb = __builtin_amdgcn_readfirstlane(
                (unsigned int)(uintptr_t)(lds + buf * 32768 + 16384 + w * 1024));
            asm volatile("s_mov_b32 m0, %0\n\t"
                         "global_load_lds_dwordx4 %1, off"
                         :: "s"(lb), "v"(g) : "memory");
        }
    };

    const int kt_start = (qt < 2) ? (8 - 4 * qt) : 0;
    stageKV(kt_start, 0);
    int cur = 0;

    for (int kt = kt_start; kt < 12; ++kt) {
        asm volatile("s_waitcnt vmcnt(0)" ::: "memory");
        __syncthreads();
        if (kt + 1 < 12) stageKV(kt + 1, cur ^ 1);

        const int gk0 = q0 - 512 + kt * 64;
        const char* ldsb = lds + cur * 32768;
        const int qlo = q0 + w * 16;
        const bool active = (gk0 <= qlo + 15) && (gk0 + 63 >= qlo - 512);
        if (active) {
            const int dqw = qlo - gk0;
            bool kbok[4];
#pragma unroll
            for (int kb = 0; kb < 4; ++kb)
                kbok[kb] = (kb * 16 <= dqw + 15) && (kb * 16 + 15 >= dqw - 512);

            f32x4 s4[4];
#pragma unroll
            for (int kb = 0; kb < 4; ++kb) s4[kb] = (f32x4)0.f;
#pragma unroll
            for (int kb = 0; kb < 4; ++kb) {
                if (kbok[kb]) {
#pragma unroll
                    for (int kw = 0; kw < 4; ++kw) {
                        short8 kf = *(const short8*)(ldsb + (kb * 16 + l16) * 256
                                                     + (((kw * 4 + kg) ^ (l16 & 7)) << 4));
                        s4[kb] = __builtin_amdgcn_mfma_f32_16x16x32_bf16(
                            kf, qf[kw], s4[kb], 0, 0, 0);
                    }
                }
            }

            const int dq = gq - gk0;
            float p[4][4];
            float tm = -1e30f;
#pragma unroll
            for (int kb = 0; kb < 4; ++kb)
#pragma unroll
                for (int r = 0; r < 4; ++r) {
                    const int koff = kb * 16 + kg * 4 + r;
                    const bool valid = (koff <= dq) && (koff >= dq - 512);
                    const float sv = valid ? s4[kb][r] * SCL2E : -1e30f;
                    p[kb][r] = sv;
                    tm = fmaxf(tm, sv);
                }
            tm = fmaxf(tm, __shfl_xor(tm, 16));
            tm = fmaxf(tm, __shfl_xor(tm, 32));
            const float mn   = fmaxf(m, tm);
            const float corr = __builtin_amdgcn_exp2f(m - mn);
            m = mn;
            l *= corr;
            float cr[4];
#pragma unroll
            for (int r = 0; r < 4; ++r) cr[r] = __shfl(corr, kg * 4 + r);
#pragma unroll
            for (int db = 0; db < 8; ++db)
#pragma unroll
                for (int r = 0; r < 4; ++r) acc_o[db][r] *= cr[r];

            float ts = 0.f;
#pragma unroll
            for (int kb = 0; kb < 4; ++kb)
#pragma unroll
                for (int r = 0; r < 4; ++r) {
                    const float pv = (p[kb][r] > -1e29f)
                                         ? __builtin_amdgcn_exp2f(p[kb][r] - m) : 0.f;
                    p[kb][r] = pv;
                    ts += pv;
                }
            ts += __shfl_xor(ts, 16);
            ts += __shfl_xor(ts, 32);
            l += ts;

            unsigned int dw[4][2];
#pragma unroll
            for (int kb = 0; kb < 4; ++kb) {
                dw[kb][0] = cvt_pk_bf16(p[kb][0], p[kb][1]);
                dw[kb][1] = cvt_pk_bf16(p[kb][2], p[kb][3]);
            }
#pragma unroll
            for (int w2 = 0; w2 < 2; ++w2) {
                if (!(kbok[2 * w2] || kbok[2 * w2 + 1])) continue;
                union { unsigned int u[4]; short8 v; } pu;
                pu.u[0] = dw[2 * w2][0];     pu.u[1] = dw[2 * w2][1];
                pu.u[2] = dw[2 * w2 + 1][0]; pu.u[3] = dw[2 * w2 + 1][1];
#pragma unroll
                for (int db = 0; db < 8; ++db) {
                    short8 vf = *(const short8*)(ldsb + 16384 + (db * 16 + l16) * 128
                                                 + (((w2 * 4 + kg) ^ (l16 & 7)) << 4));
                    acc_o[db] = __builtin_amdgcn_mfma_f32_16x16x32_bf16(
                        pu.v, vf, acc_o[db], 0, 0, 0);
                }
            }
        }
        cur ^= 1;
    }

    const float inv = 1.0f / l;
    float li[4];
#pragma unroll
    for (int r = 0; r < 4; ++r) li[r] = __shfl(inv, kg * 4 + r);
#pragma unroll
    for (int db = 0; db < 8; ++db)
#pragma unroll
        for (int r = 0; r < 4; ++r) {
            const int gqr = q0 + w * 16 + kg * 4 + r;
            O[((size_t)b * SEQ + gqr) * EMBED + h * HDIM + db * 16 + l16] =
                f2bf(acc_o[db][r] * li[r]);
        }
}

// ---------------------------------------------------------------------------
extern "C" void kernel_launch(void* const* d_in, const int* in_sizes, int n_in,
                              void* d_out, int out_size, void* d_ws, size_t ws_size,
                              hipStream_t stream)
{
    const float* x     = (const float*)d_in[0];
    const float* w_qkv = (const float*)d_in[1];
    const float* w_out = (const float*)d_in[2];
    float* out = (float*)d_out;

    char* ws = (char*)d_ws;
    unsigned short* xb    = (unsigned short*)(ws);
    unsigned short* wqkvb = (unsigned short*)(ws + 33554432);
    unsigned short* woutb = (unsigned short*)(ws + 58720256);
    unsigned short* qb    = (unsigned short*)(ws + 67108864);
    unsigned short* kb    = (unsigned short*)(ws + 100663296);
    unsigned short* vtb   = (unsigned short*)(ws + 134217728);
    unsigned short* attnb = (unsigned short*)(ws + 167772160);

    const int M = BATCH * SEQ;  // 8192
    dim3 blk(256);

    // merged casts
    hipLaunchKernelGGL(cast3_kernel, dim3(16384), blk, 0, stream,
                       x, w_qkv, w_out, xb, wqkvb, woutb);

    // Q,K projection: A = x [8192,2048], B = Wqk rows 0..4095 -> grid (16,32)
    hipLaunchKernelGGL((gemm256_kernel<1>), dim3(16, 32), dim3(512), 0, stream,
                       xb, wqkvb, (float*)nullptr, qb, kb, M, 2 * EMBED, EMBED);

    // V^T projection: A = Wv [2048,2048], B = x [8192,2048] -> grid (32,8)
    hipLaunchKernelGGL((gemm256_kernel<2>), dim3(32, 8), dim3(512), 0, stream,
                       wqkvb + (size_t)2 * EMBED * EMBED, xb, (float*)nullptr,
                       vtb, (unsigned short*)nullptr, EMBED, M, EMBED);

    // attention: QBLK=256 -> 512 blocks x 1024 threads
    hipLaunchKernelGGL(swa_mfma_kernel, dim3(BATCH * HEADS * (SEQ / 256)), dim3(1024),
                       0, stream, qb, kb, vtb, attnb);

    // out projection: grid (8,32)
    hipLaunchKernelGGL((gemm256_kernel<0>), dim3(8, 32), dim3(512), 0, stream,
                       attnb, woutb, out, (unsigned short*)nullptr,
                       (unsigned short*)nullptr, M, EMBED, EMBED);
}

// Round 15
// 329.154 us; speedup vs baseline: 1.0265x; 1.0053x over previous
//
#include <hip/hip_runtime.h>
#include <hip/hip_bf16.h>
#include <math.h>

// Stage 0: single merged cast kernel: x, w_qkv, w_out -> bf16
// Stage 1a: 256^2 bf16 MFMA GEMM (x * Wqk^T) -> q,k bf16 [B,H,S,128]
// Stage 1b: same (Wv * x^T) -> vt bf16 [B,H,128,S], sigma baked in
// Stage 2: MFMA flash attention (window=512, QBLK=256, dbuf KV, kb-skip,
//          defer-max T13, setprio T5)
// Stage 3: same GEMM -> d_out fp32
//
// GEMM K-loop (R10-validated): full LDS double-buffer, ONE __syncthreads per
// tile; 24 ds_read_b128 + 64 MFMA barrier-free interval; all K-loop VMEM is
// asm gload_lds (single accounting).

#define SEQ   4096
#define BATCH 2
#define EMBED 2048
#define HEADS 16
#define HDIM  128
#define NELEM (BATCH * SEQ * EMBED)  // 16777216
#define SCL2E (0.088388347648318447f * 1.4426950408889634f)  // 1/sqrt(128)*log2(e)

typedef __attribute__((ext_vector_type(8))) short short8;
typedef __attribute__((ext_vector_type(4))) float f32x4;

__device__ __forceinline__ unsigned short f2bf(float f) {
    unsigned int u = __float_as_uint(f);
    u = (u + 0x7fff + ((u >> 16) & 1)) >> 16;  // round-to-nearest-even
    return (unsigned short)u;
}

__device__ __forceinline__ unsigned int cvt_pk_bf16(float a, float b) {
    unsigned int r;
    asm volatile("v_cvt_pk_bf16_f32 %0, %1, %2" : "=v"(r) : "v"(a), "v"(b));
    return r;
}

// ---------------------------------------------------------------------------
// merged fp32 -> bf16 cast for all three inputs, 8 elems/thread
// ---------------------------------------------------------------------------
__global__ void cast3_kernel(const float* __restrict__ x,
                             const float* __restrict__ wq,
                             const float* __restrict__ wo,
                             unsigned short* __restrict__ xb,
                             unsigned short* __restrict__ wqb,
                             unsigned short* __restrict__ wob)
{
    const int nx = NELEM / 8;
    const int nq = 3 * EMBED * EMBED / 8;
    const int no = EMBED * EMBED / 8;
    int i = blockIdx.x * blockDim.x + threadIdx.x;
    const float* s;
    unsigned short* d;
    int j;
    if (i < nx)                { s = x;  d = xb;  j = i; }
    else if (i < nx + nq)      { s = wq; d = wqb; j = i - nx; }
    else if (i < nx + nq + no) { s = wo; d = wob; j = i - nx - nq; }
    else return;
    const float4 v0 = ((const float4*)s)[2 * j];
    const float4 v1 = ((const float4*)s)[2 * j + 1];
    union { unsigned short us[8]; uint4 u4; } o;
    o.us[0] = f2bf(v0.x); o.us[1] = f2bf(v0.y); o.us[2] = f2bf(v0.z); o.us[3] = f2bf(v0.w);
    o.us[4] = f2bf(v1.x); o.us[5] = f2bf(v1.y); o.us[6] = f2bf(v1.z); o.us[7] = f2bf(v1.w);
    ((uint4*)d)[j] = o.u4;
}

// ---------------------------------------------------------------------------
// 256x256 bf16 NT-GEMM: C[M,N] = A[M,K]*B[N,K]^T, fp32 accum. 512 thr, 8 waves
// (2M x 4N), per-wave 128x64 (acc[8][4]). BK=64, double-buffered 128 KiB LDS.
// MODE 0: C fp32 [M,N];  MODE 1: scatter bf16 q/k [B,H,S,128];
// MODE 2: scatter bf16 vt [B,H,128,S] with sigma permutation.
// ---------------------------------------------------------------------------
template <int MODE>
__global__ __launch_bounds__(512)
void gemm256_kernel(const unsigned short* __restrict__ A,
                    const unsigned short* __restrict__ B,
                    float* __restrict__ C,
                    unsigned short* __restrict__ P0,
                    unsigned short* __restrict__ P1,
                    int M, int N, int K)
{
    // Abuf[p] @ p*32768; Bbuf[p] @ 65536 + p*32768
    __shared__ __align__(16) char lds[131072];

    const int tid  = threadIdx.x;
    const int lane = tid & 63;
    const int w    = tid >> 6;       // 0..7
    const int wm   = w >> 2;         // 0..1
    const int wn   = w & 3;          // 0..3
    const int l16  = lane & 15;
    const int kg   = lane >> 4;

    // m-major XCD chunking (R5-validated)
    const int nwg  = gridDim.x * gridDim.y;
    const int bidl = blockIdx.y * gridDim.x + blockIdx.x;
    const int cpx  = nwg >> 3;
    const int swzb = (bidl & 7) * cpx + (bidl >> 3);
    const int m0   = (swzb / gridDim.x) * 256;
    const int n0   = (swzb % gridDim.x) * 256;

    // staging: per instr u, rows u*64 + w*8 + (lane>>3); source chunk
    // pre-swizzled so LDS[row][ch] = global[row][ch ^ (row&7)].
    const int srow = w * 8 + (lane >> 3);
    const int sch8 = ((lane & 7) ^ (lane >> 3)) * 8;

    auto stage = [&](const unsigned short* X, int rowbase, int t2, int ldsbase) {
#pragma unroll
        for (int u = 0; u < 2; ++u) {
            const unsigned short* g = X + (size_t)(rowbase + u * 64 + srow) * K
                                      + t2 * 64 + sch8;
            unsigned int lb = __builtin_amdgcn_readfirstlane(
                (unsigned int)(uintptr_t)(lds + ldsbase + u * 8192 + w * 1024));
            asm volatile("s_mov_b32 m0, %0\n\t"
                         "global_load_lds_dwordx4 %1, off"
                         :: "s"(lb), "v"(g) : "memory");
        }
    };
    auto rdA = [&](int p, int mf, int ks) -> short8 {
        return *(const short8*)(lds + p * 32768 + (wm * 128 + mf * 16 + l16) * 128
                                + (((ks * 4 + kg) ^ (l16 & 7)) << 4));
    };
    auto rdB = [&](int p, int nf, int ks) -> short8 {
        return *(const short8*)(lds + 65536 + p * 32768
                                + (wn * 64 + nf * 16 + l16) * 128
                                + (((ks * 4 + kg) ^ (l16 & 7)) << 4));
    };

    f32x4 acc[8][4];
#pragma unroll
    for (int i = 0; i < 8; ++i)
#pragma unroll
        for (int j = 0; j < 4; ++j) acc[i][j] = (f32x4)0.f;

    const int NT = K >> 6;  // K-tiles of 64 (K=2048 -> 32)

    // prologue: stage tile 0 into bufs 0; drain + barrier.
    stage(A, m0 + 0,   0, 0);
    stage(A, m0 + 128, 0, 16384);
    stage(B, n0 + 0,   0, 65536);
    stage(B, n0 + 128, 0, 65536 + 16384);
    __syncthreads();

    for (int t = 0; t < NT; ++t) {
        const int p = t & 1;
        // prefetch tile t+1 into bufs p^1 (issue first: max HBM-latency cover)
        if (t + 1 < NT) {
            stage(A, m0 + 0,   t + 1, (p ^ 1) * 32768);
            stage(A, m0 + 128, t + 1, (p ^ 1) * 32768 + 16384);
            stage(B, n0 + 0,   t + 1, 65536 + (p ^ 1) * 32768);
            stage(B, n0 + 128, t + 1, 65536 + (p ^ 1) * 32768 + 16384);
        }
        // barrier-free interval: 24 ds_reads + 64 MFMAs, compiler-interleaved
        short8 bfr[4][2];
#pragma unroll
        for (int nf = 0; nf < 4; ++nf)
#pragma unroll
            for (int ks = 0; ks < 2; ++ks) bfr[nf][ks] = rdB(p, nf, ks);
#pragma unroll
        for (int mf = 0; mf < 8; ++mf) {
            const short8 a0 = rdA(p, mf, 0);
            const short8 a1 = rdA(p, mf, 1);
#pragma unroll
            for (int nf = 0; nf < 4; ++nf) {
                acc[mf][nf] = __builtin_amdgcn_mfma_f32_16x16x32_bf16(
                    a0, bfr[nf][0], acc[mf][nf], 0, 0, 0);
                acc[mf][nf] = __builtin_amdgcn_mfma_f32_16x16x32_bf16(
                    a1, bfr[nf][1], acc[mf][nf], 0, 0, 0);
            }
        }
        // single boundary: vmcnt(0)+lgkmcnt(0)+s_barrier (compiler-emitted);
        // staged loads are ~1 tile old -> drain is cheap.
        __syncthreads();
    }

    // epilogue (R10-validated scatter)
    if (MODE == 1) {
        const int cb = n0 + wn * 64;          // 64-col wave tile: one head slice
        unsigned short* dst = (cb >> 11) ? P1 : P0;
        const int h  = (cb >> 7) & 15;
        const int db = cb & 127;
#pragma unroll
        for (int fi = 0; fi < 8; ++fi)
#pragma unroll
            for (int r = 0; r < 4; ++r) {
                const int mrow = m0 + wm * 128 + fi * 16 + kg * 4 + r;
                const int b = mrow >> 12, s = mrow & 4095;
                unsigned short* drow = dst + ((size_t)((b << 4) + h) * SEQ + s) * HDIM
                                       + db + l16;
#pragma unroll
                for (int nf = 0; nf < 4; ++nf) drow[nf * 16] = f2bf(acc[fi][nf][r]);
            }
    } else if (MODE == 2) {
#pragma unroll
        for (int fi = 0; fi < 8; ++fi)
#pragma unroll
            for (int r = 0; r < 4; ++r) {
                const int mrow = m0 + wm * 128 + fi * 16 + kg * 4 + r;
                const int h = mrow >> 7, d = mrow & 127;
#pragma unroll
                for (int nf = 0; nf < 4; ++nf) {
                    const int col = n0 + wn * 64 + nf * 16 + l16;
                    const int b = col >> 12, s = col & 4095;
                    const int sl = s & 63;
                    const int c = (sl & 0x23) | ((sl & 0x0C) << 1) | ((sl & 0x10) >> 2);
                    P0[((size_t)((b << 4) + h) * HDIM + d) * SEQ + (s & ~63) + c] =
                        f2bf(acc[fi][nf][r]);
                }
            }
    } else {
#pragma unroll
        for (int fi = 0; fi < 8; ++fi)
#pragma unroll
            for (int r = 0; r < 4; ++r) {
                float* crow = C + (size_t)(m0 + wm * 128 + fi * 16 + kg * 4 + r) * N
                              + n0 + wn * 64 + l16;
#pragma unroll
                for (int nf = 0; nf < 4; ++nf) crow[nf * 16] = acc[fi][nf][r];
            }
    }
}

// ---------------------------------------------------------------------------
// MFMA flash attention, QBLK=256 (R13-validated): 1024 thr = 16 waves, each
// owning 16 queries; 12 KV tiles of 64 per block. Per buf: K [64 keys][128 d]
// @ +0, Vt [128 d][64 sigma-keys] @ +16384; bufs @ 0/32768. Swapped QK^T;
// P lane-local via sigma; dbuf KV; wave-uniform kb-skip.
// R15: + T13 defer-max (skip O-rescale while max grows <= 8 in log2 units;
// P bounded by 2^8, fp32 l/acc safe) and T5 setprio around MFMA clusters.
// ---------------------------------------------------------------------------
__global__ __launch_bounds__(1024)
void swa_mfma_kernel(const unsigned short* __restrict__ Qg,
                     const unsigned short* __restrict__ Kg,
                     const unsigned short* __restrict__ Vtg,
                     unsigned short* __restrict__ O /* bf16 [B,S,E] */)
{
    __shared__ __align__(16) char lds[65536];

    const int bid = blockIdx.x;
    const int qt  = bid & 15;            // SEQ/256 = 16 query tiles
    const int h   = (bid >> 4) & 15;
    const int b   = bid >> 8;
    const int q0  = qt * 256;
    const int tid  = threadIdx.x;
    const int w    = tid >> 6;           // 0..15
    const int lane = tid & 63;
    const int l16  = lane & 15;
    const int kg   = lane >> 4;
    const size_t base = (size_t)((b << 4) + h) * SEQ * HDIM;
    const int gq = q0 + w * 16 + l16;

    short8 qf[4];
#pragma unroll
    for (int kw = 0; kw < 4; ++kw)
        qf[kw] = *(const short8*)(Qg + base + (size_t)gq * HDIM + kw * 32 + kg * 8);

    f32x4 acc_o[8];
#pragma unroll
    for (int db = 0; db < 8; ++db) acc_o[db] = (f32x4)0.f;
    float m = -1e30f, l = 0.f;

    auto stageKV = [&](int kt, int buf) {
        const int gk0 = q0 - 512 + kt * 64;
        {   // K: 1024 chunks, row=key (tid>>4), 16 chunks/row, swz ch^(row&7)
            const int row = tid >> 4, ch = tid & 15;
            const char* g = (const char*)(Kg + base + (size_t)(gk0 + row) * HDIM
                                          + ((ch ^ (row & 7)) << 3));
            unsigned int lb = __builtin_amdgcn_readfirstlane(
                (unsigned int)(uintptr_t)(lds + buf * 32768 + w * 1024));
            asm volatile("s_mov_b32 m0, %0\n\t"
                         "global_load_lds_dwordx4 %1, off"
                         :: "s"(lb), "v"(g) : "memory");
        }
        {   // Vt: row=d (tid>>3), 8 chunks/row, swz ch^(d&7)
            const int d = tid >> 3, ch = tid & 7;
            const char* g = (const char*)(Vtg + base + (size_t)d * SEQ + gk0
                                          + ((ch ^ (d & 7)) << 3));
            unsigned int lb = __builtin_amdgcn_readfirstlane(
                (unsigned int)(uintptr_t)(lds + buf * 32768 + 16384 + w * 1024));
            asm volatile("s_mov_b32 m0, %0\n\t"
                         "global_load_lds_dwordx4 %1, off"
                         :: "s"(lb), "v"(g) : "memory");
        }
    };

    const int kt_start = (qt < 2) ? (8 - 4 * qt) : 0;
    stageKV(kt_start, 0);
    int cur = 0;

    for (int kt = kt_start; kt < 12; ++kt) {
        asm volatile("s_waitcnt vmcnt(0)" ::: "memory");
        __syncthreads();
        if (kt + 1 < 12) stageKV(kt + 1, cur ^ 1);

        const int gk0 = q0 - 512 + kt * 64;
        const char* ldsb = lds + cur * 32768;
        const int qlo = q0 + w * 16;
        const bool active = (gk0 <= qlo + 15) && (gk0 + 63 >= qlo - 512);
        if (active) {
            const int dqw = qlo - gk0;
            bool kbok[4];
#pragma unroll
            for (int kb = 0; kb < 4; ++kb)
                kbok[kb] = (kb * 16 <= dqw + 15) && (kb * 16 + 15 >= dqw - 512);

            f32x4 s4[4];
#pragma unroll
            for (int kb = 0; kb < 4; ++kb) s4[kb] = (f32x4)0.f;
            __builtin_amdgcn_s_setprio(1);
#pragma unroll
            for (int kb = 0; kb < 4; ++kb) {
                if (kbok[kb]) {
#pragma unroll
                    for (int kw = 0; kw < 4; ++kw) {
                        short8 kf = *(const short8*)(ldsb + (kb * 16 + l16) * 256
                                                     + (((kw * 4 + kg) ^ (l16 & 7)) << 4));
                        s4[kb] = __builtin_amdgcn_mfma_f32_16x16x32_bf16(
                            kf, qf[kw], s4[kb], 0, 0, 0);
                    }
                }
            }
            __builtin_amdgcn_s_setprio(0);

            const int dq = gq - gk0;
            float p[4][4];
            float tm = -1e30f;
#pragma unroll
            for (int kb = 0; kb < 4; ++kb)
#pragma unroll
                for (int r = 0; r < 4; ++r) {
                    const int koff = kb * 16 + kg * 4 + r;
                    const bool valid = (koff <= dq) && (koff >= dq - 512);
                    const float sv = valid ? s4[kb][r] * SCL2E : -1e30f;
                    p[kb][r] = sv;
                    tm = fmaxf(tm, sv);
                }
            tm = fmaxf(tm, __shfl_xor(tm, 16));
            tm = fmaxf(tm, __shfl_xor(tm, 32));

            // T13 defer-max: keep stale m while growth <= 8 (log2) -> P <= 256
            if (!__all(tm <= m + 8.0f)) {
                const float mn   = fmaxf(m, tm);
                const float corr = __builtin_amdgcn_exp2f(m - mn);
                m = mn;
                l *= corr;
                float cr[4];
#pragma unroll
                for (int r = 0; r < 4; ++r) cr[r] = __shfl(corr, kg * 4 + r);
#pragma unroll
                for (int db = 0; db < 8; ++db)
#pragma unroll
                    for (int r = 0; r < 4; ++r) acc_o[db][r] *= cr[r];
            }

            float ts = 0.f;
#pragma unroll
            for (int kb = 0; kb < 4; ++kb)
#pragma unroll
                for (int r = 0; r < 4; ++r) {
                    const float pv = (p[kb][r] > -1e29f)
                                         ? __builtin_amdgcn_exp2f(p[kb][r] - m) : 0.f;
                    p[kb][r] = pv;
                    ts += pv;
                }
            ts += __shfl_xor(ts, 16);
            ts += __shfl_xor(ts, 32);
            l += ts;

            unsigned int dw[4][2];
#pragma unroll
            for (int kb = 0; kb < 4; ++kb) {
                dw[kb][0] = cvt_pk_bf16(p[kb][0], p[kb][1]);
                dw[kb][1] = cvt_pk_bf16(p[kb][2], p[kb][3]);
            }
            __builtin_amdgcn_s_setprio(1);
#pragma unroll
            for (int w2 = 0; w2 < 2; ++w2) {
                if (!(kbok[2 * w2] || kbok[2 * w2 + 1])) continue;
                union { unsigned int u[4]; short8 v; } pu;
                pu.u[0] = dw[2 * w2][0];     pu.u[1] = dw[2 * w2][1];
                pu.u[2] = dw[2 * w2 + 1][0]; pu.u[3] = dw[2 * w2 + 1][1];
#pragma unroll
                for (int db = 0; db < 8; ++db) {
                    short8 vf = *(const short8*)(ldsb + 16384 + (db * 16 + l16) * 128
                                                 + (((w2 * 4 + kg) ^ (l16 & 7)) << 4));
                    acc_o[db] = __builtin_amdgcn_mfma_f32_16x16x32_bf16(
                        pu.v, vf, acc_o[db], 0, 0, 0);
                }
            }
            __builtin_amdgcn_s_setprio(0);
        }
        cur ^= 1;
    }

    const float inv = 1.0f / l;
    float li[4];
#pragma unroll
    for (int r = 0; r < 4; ++r) li[r] = __shfl(inv, kg * 4 + r);
#pragma unroll
    for (int db = 0; db < 8; ++db)
#pragma unroll
        for (int r = 0; r < 4; ++r) {
            const int gqr = q0 + w * 16 + kg * 4 + r;
            O[((size_t)b * SEQ + gqr) * EMBED + h * HDIM + db * 16 + l16] =
                f2bf(acc_o[db][r] * li[r]);
        }
}

// ---------------------------------------------------------------------------
extern "C" void kernel_launch(void* const* d_in, const int* in_sizes, int n_in,
                              void* d_out, int out_size, void* d_ws, size_t ws_size,
                              hipStream_t stream)
{
    const float* x     = (const float*)d_in[0];
    const float* w_qkv = (const float*)d_in[1];
    const float* w_out = (const float*)d_in[2];
    float* out = (float*)d_out;

    char* ws = (char*)d_ws;
    unsigned short* xb    = (unsigned short*)(ws);
    unsigned short* wqkvb = (unsigned short*)(ws + 33554432);
    unsigned short* woutb = (unsigned short*)(ws + 58720256);
    unsigned short* qb    = (unsigned short*)(ws + 67108864);
    unsigned short* kb    = (unsigned short*)(ws + 100663296);
    unsigned short* vtb   = (unsigned short*)(ws + 134217728);
    unsigned short* attnb = (unsigned short*)(ws + 167772160);

    const int M = BATCH * SEQ;  // 8192
    dim3 blk(256);

    // merged casts
    hipLaunchKernelGGL(cast3_kernel, dim3(16384), blk, 0, stream,
                       x, w_qkv, w_out, xb, wqkvb, woutb);

    // Q,K projection: A = x [8192,2048], B = Wqk rows 0..4095 -> grid (16,32)
    hipLaunchKernelGGL((gemm256_kernel<1>), dim3(16, 32), dim3(512), 0, stream,
                       xb, wqkvb, (float*)nullptr, qb, kb, M, 2 * EMBED, EMBED);

    // V^T projection: A = Wv [2048,2048], B = x [8192,2048] -> grid (32,8)
    hipLaunchKernelGGL((gemm256_kernel<2>), dim3(32, 8), dim3(512), 0, stream,
                       wqkvb + (size_t)2 * EMBED * EMBED, xb, (float*)nullptr,
                       vtb, (unsigned short*)nullptr, EMBED, M, EMBED);

    // attention: QBLK=256 -> 512 blocks x 1024 threads
    hipLaunchKernelGGL(swa_mfma_kernel, dim3(BATCH * HEADS * (SEQ / 256)), dim3(1024),
                       0, stream, qb, kb, vtb, attnb);

    // out projection: grid (8,32)
    hipLaunchKernelGGL((gemm256_kernel<0>), dim3(8, 32), dim3(512), 0, stream,
                       attnb, woutb, out, (unsigned short*)nullptr,
                       (unsigned short*)nullptr, M, EMBED, EMBED);
}